// Round 1
// baseline (586.361 us; speedup 1.0000x reference)
//
#include <hip/hip_runtime.h>
#include <hip/hip_bf16.h>
#include <cstdint>

#define DIM 128

// ---------------- histogram: in-degree counts at dst ----------------
__global__ __launch_bounds__(256) void hist_kernel(const int* __restrict__ dst,
                                                   int* __restrict__ counts, int E) {
    int e = blockIdx.x * 256 + threadIdx.x;
    if (e < E) atomicAdd(&counts[dst[e]], 1);
}

// ---------------- single-block scan: counts -> CSR offsets, cursor, dinv ----------------
__global__ __launch_bounds__(1024) void scan_kernel(const int* __restrict__ counts,
                                                    int* __restrict__ offsets,
                                                    int* __restrict__ cursor,
                                                    float* __restrict__ dinv, int N) {
    __shared__ int wsum[16];
    __shared__ int carry_s;
    int tid = threadIdx.x, lane = tid & 63, wid = tid >> 6;
    if (tid == 0) carry_s = 0;
    __syncthreads();
    for (int base = 0; base < N; base += 1024) {
        int i = base + tid;
        int c = (i < N) ? counts[i] : 0;
        // inclusive wave scan
        int v = c;
        #pragma unroll
        for (int d = 1; d < 64; d <<= 1) {
            int t = __shfl_up(v, d, 64);
            if (lane >= d) v += t;
        }
        if (lane == 63) wsum[wid] = v;
        __syncthreads();
        if (wid == 0) {
            int t = (lane < 16) ? wsum[lane] : 0;
            #pragma unroll
            for (int d = 1; d < 16; d <<= 1) {
                int u = __shfl_up(t, d, 64);
                if (lane >= d) t += u;
            }
            if (lane < 16) wsum[lane] = t;  // inclusive over wave sums
        }
        __syncthreads();
        int waveoff = (wid == 0) ? 0 : wsum[wid - 1];
        int excl = carry_s + waveoff + (v - c);
        if (i < N) {
            offsets[i] = excl;
            cursor[i]  = excl;
            dinv[i]    = rsqrtf((float)(c + 1));  // +1 self loop; always > 0
        }
        int blocktotal = wsum[15];
        __syncthreads();  // all reads of carry_s/wsum done
        if (tid == 0) carry_s += blocktotal;
        __syncthreads();  // carry visible; wsum reusable
    }
    if (threadIdx.x == 0) offsets[N] = carry_s;
}

// ---------------- scatter edges into CSR order by dst ----------------
__global__ __launch_bounds__(256) void scatter_kernel(const int* __restrict__ src,
                                                      const int* __restrict__ dst,
                                                      int* __restrict__ cursor,
                                                      int* __restrict__ csr_src, int E) {
    int e = blockIdx.x * 256 + threadIdx.x;
    if (e < E) {
        int d = dst[e];
        int pos = atomicAdd(&cursor[d], 1);
        csr_src[pos] = src[e];
    }
}

// ---------------- aggregation in x-domain: out[i] = dinv[i]*(sum_e dinv[s]*x[s] + dinv[i]*x[i]) ----------------
__global__ __launch_bounds__(256) void agg_kernel(const float* __restrict__ x,
                                                  const int* __restrict__ csr_src,
                                                  const int* __restrict__ offsets,
                                                  const float* __restrict__ dinv,
                                                  float* __restrict__ out, int N) {
    int lane = threadIdx.x & 63;
    int wid  = __builtin_amdgcn_readfirstlane((int)(threadIdx.x >> 6));
    int node = blockIdx.x * 4 + wid;
    if (node >= N) return;
    int beg = offsets[node];
    int end = offsets[node + 1];
    float di = dinv[node];
    // self-loop contribution: dinv[i]^2 * x[i]  (outer di applied at the end)
    float2 acc = ((const float2*)(x + (size_t)node * DIM))[lane];
    acc.x *= di; acc.y *= di;
    int j = beg;
    for (; j + 4 <= end; j += 4) {
        int s0 = csr_src[j + 0], s1 = csr_src[j + 1];
        int s2 = csr_src[j + 2], s3 = csr_src[j + 3];
        float w0 = dinv[s0], w1 = dinv[s1], w2 = dinv[s2], w3 = dinv[s3];
        float2 v0 = ((const float2*)(x + (size_t)s0 * DIM))[lane];
        float2 v1 = ((const float2*)(x + (size_t)s1 * DIM))[lane];
        float2 v2 = ((const float2*)(x + (size_t)s2 * DIM))[lane];
        float2 v3 = ((const float2*)(x + (size_t)s3 * DIM))[lane];
        acc.x += w0 * v0.x; acc.y += w0 * v0.y;
        acc.x += w1 * v1.x; acc.y += w1 * v1.y;
        acc.x += w2 * v2.x; acc.y += w2 * v2.y;
        acc.x += w3 * v3.x; acc.y += w3 * v3.y;
    }
    for (; j < end; ++j) {
        int s = csr_src[j];
        float w = dinv[s];
        float2 v = ((const float2*)(x + (size_t)s * DIM))[lane];
        acc.x += w * v.x; acc.y += w * v.y;
    }
    acc.x *= di; acc.y *= di;
    ((float2*)(out + (size_t)node * DIM))[lane] = acc;
}

// ---------------- in-place GEMM + bias + PReLU: io = prelu(io @ W + b) ----------------
// wave handles 8 rows; lane handles cols (lane, lane+64). Row values come in via
// wave-uniform addresses -> s_load_dwordx4 (SGPR operands), W loads coalesced + cached.
__global__ __launch_bounds__(256) void gemm_kernel(float* __restrict__ io,
                                                   const float* __restrict__ W,
                                                   const float* __restrict__ b,
                                                   const float* __restrict__ alpha, int N) {
    int lane = threadIdx.x & 63;
    int wid  = __builtin_amdgcn_readfirstlane((int)(threadIdx.x >> 6));
    int rowbase = (blockIdx.x * 4 + wid) * 8;
    const int c0 = lane, c1 = lane + 64;
    float acc0[8], acc1[8];
    #pragma unroll
    for (int r = 0; r < 8; ++r) { acc0[r] = 0.f; acc1[r] = 0.f; }
    for (int k = 0; k < DIM; k += 4) {
        float w00 = W[(k + 0) * DIM + c0], w01 = W[(k + 1) * DIM + c0];
        float w02 = W[(k + 2) * DIM + c0], w03 = W[(k + 3) * DIM + c0];
        float w10 = W[(k + 0) * DIM + c1], w11 = W[(k + 1) * DIM + c1];
        float w12 = W[(k + 2) * DIM + c1], w13 = W[(k + 3) * DIM + c1];
        #pragma unroll
        for (int r = 0; r < 8; ++r) {
            int row = rowbase + r;
            row = row < N ? row : N - 1;  // clamp (N is an exact multiple; no-op in practice)
            float4 rv = ((const float4*)(io + (size_t)row * DIM))[k >> 2];
            acc0[r] += rv.x * w00 + rv.y * w01 + rv.z * w02 + rv.w * w03;
            acc1[r] += rv.x * w10 + rv.y * w11 + rv.z * w12 + rv.w * w13;
        }
    }
    float bb0 = b[c0], bb1 = b[c1], a0 = alpha[c0], a1 = alpha[c1];
    #pragma unroll
    for (int r = 0; r < 8; ++r) {
        int row = rowbase + r;
        if (row < N) {
            float v0 = acc0[r] + bb0; v0 = v0 > 0.f ? v0 : a0 * v0;
            float v1 = acc1[r] + bb1; v1 = v1 > 0.f ? v1 : a1 * v1;
            io[(size_t)row * DIM + c0] = v0;
            io[(size_t)row * DIM + c1] = v1;
        }
    }
}

extern "C" void kernel_launch(void* const* d_in, const int* in_sizes, int n_in,
                              void* d_out, int out_size, void* d_ws, size_t ws_size,
                              hipStream_t stream) {
    const float* x     = (const float*)d_in[0];
    const int*   ei    = (const int*)d_in[1];   // [2, E] -> src row then dst row
    const float* W     = (const float*)d_in[2];
    const float* b     = (const float*)d_in[3];
    const float* alpha = (const float*)d_in[4];
    float* out = (float*)d_out;

    int N = in_sizes[0] / DIM;
    int E = in_sizes[1] / 2;
    const int* src = ei;
    const int* dst = ei + E;

    // workspace carve-out (~8 MB total)
    char* ws = (char*)d_ws;
    size_t off = 0;
    auto alloc = [&](size_t bytes) -> char* {
        char* p = ws + off;
        off += (bytes + 255) & ~(size_t)255;
        return p;
    };
    int*   counts  = (int*)alloc((size_t)N * 4);
    int*   offsets = (int*)alloc((size_t)(N + 1) * 4);
    int*   cursor  = (int*)alloc((size_t)N * 4);
    float* dinv    = (float*)alloc((size_t)N * 4);
    int*   csr_src = (int*)alloc((size_t)E * 4);

    hipMemsetAsync(counts, 0, (size_t)N * 4, stream);
    hist_kernel<<<(E + 255) / 256, 256, 0, stream>>>(dst, counts, E);
    scan_kernel<<<1, 1024, 0, stream>>>(counts, offsets, cursor, dinv, N);
    scatter_kernel<<<(E + 255) / 256, 256, 0, stream>>>(src, dst, cursor, csr_src, E);
    agg_kernel<<<(N + 3) / 4, 256, 0, stream>>>(x, csr_src, offsets, dinv, out, N);
    gemm_kernel<<<(N + 31) / 32, 256, 0, stream>>>(out, W, b, alpha, N);
}

// Round 2
// 506.719 us; speedup vs baseline: 1.1572x; 1.1572x over previous
//
#include <hip/hip_runtime.h>
#include <hip/hip_bf16.h>
#include <cstdint>

#define DIM 128
#define SCAN_BLOCK 1024

// ---------------- histogram: in-degree counts at dst ----------------
__global__ __launch_bounds__(256) void hist_kernel(const int* __restrict__ dst,
                                                   int* __restrict__ counts, int E) {
    int e = blockIdx.x * 256 + threadIdx.x;
    if (e < E) atomicAdd(&counts[dst[e]], 1);
}

// ---------------- scan stage 1: per-block sums of counts ----------------
__global__ __launch_bounds__(SCAN_BLOCK) void scan_reduce_kernel(const int* __restrict__ counts,
                                                                 int* __restrict__ bsum, int N) {
    __shared__ int wsum[16];
    int tid = threadIdx.x, lane = tid & 63, wid = tid >> 6;
    int i = blockIdx.x * SCAN_BLOCK + tid;
    int c = (i < N) ? counts[i] : 0;
    // wave reduce
    #pragma unroll
    for (int d = 32; d > 0; d >>= 1) c += __shfl_down(c, d, 64);
    if (lane == 0) wsum[wid] = c;
    __syncthreads();
    if (tid == 0) {
        int s = 0;
        #pragma unroll
        for (int w = 0; w < 16; ++w) s += wsum[w];
        bsum[blockIdx.x] = s;
    }
}

// ---------------- scan stage 2: exclusive scan of block sums (tiny) ----------------
__global__ __launch_bounds__(128) void scan_bsums_kernel(const int* __restrict__ bsum,
                                                         int* __restrict__ boff,
                                                         int* __restrict__ offsets,
                                                         int nblocks, int N) {
    __shared__ int s[256];
    int tid = threadIdx.x;
    s[tid] = (tid < nblocks) ? bsum[tid] : 0;
    s[tid + 128] = 0;
    __syncthreads();
    // Hillis-Steele inclusive scan over 128 entries
    for (int d = 1; d < 128; d <<= 1) {
        int v = (tid >= d) ? s[tid - d] : 0;
        __syncthreads();
        s[tid] += v;
        __syncthreads();
    }
    if (tid < nblocks) boff[tid] = (tid == 0) ? 0 : s[tid - 1];
    if (tid == 0) offsets[N] = s[nblocks - 1];
}

// ---------------- scan stage 3: per-block scan + apply block offset ----------------
__global__ __launch_bounds__(SCAN_BLOCK) void scan_apply_kernel(const int* __restrict__ counts,
                                                                const int* __restrict__ boff,
                                                                int* __restrict__ offsets,
                                                                int* __restrict__ cursor,
                                                                float* __restrict__ dinv, int N) {
    __shared__ int wsum[16];
    int tid = threadIdx.x, lane = tid & 63, wid = tid >> 6;
    int i = blockIdx.x * SCAN_BLOCK + tid;
    int c = (i < N) ? counts[i] : 0;
    int v = c;
    #pragma unroll
    for (int d = 1; d < 64; d <<= 1) {
        int t = __shfl_up(v, d, 64);
        if (lane >= d) v += t;
    }
    if (lane == 63) wsum[wid] = v;
    __syncthreads();
    if (wid == 0 && lane < 16) {
        int t = wsum[lane];
        #pragma unroll
        for (int d = 1; d < 16; d <<= 1) {
            int u = __shfl_up(t, d, 64);
            if (lane >= d) t += u;
        }
        wsum[lane] = t;
    }
    __syncthreads();
    int waveoff = (wid == 0) ? 0 : wsum[wid - 1];
    if (i < N) {
        int excl = boff[blockIdx.x] + waveoff + (v - c);
        offsets[i] = excl;
        cursor[i]  = excl;
        dinv[i]    = rsqrtf((float)(c + 1));  // +1 self loop; always > 0
    }
}

// ---------------- scatter edges into CSR order by dst ----------------
__global__ __launch_bounds__(256) void scatter_kernel(const int* __restrict__ src,
                                                      const int* __restrict__ dst,
                                                      int* __restrict__ cursor,
                                                      int* __restrict__ csr_src, int E) {
    int e = blockIdx.x * 256 + threadIdx.x;
    if (e < E) {
        int d = dst[e];
        int pos = atomicAdd(&cursor[d], 1);
        csr_src[pos] = src[e];
    }
}

// ---------------- pre-scale: y[i] = dinv[i] * x[i] (row-wise) ----------------
__global__ __launch_bounds__(256) void prescale_kernel(const float* __restrict__ x,
                                                       const float* __restrict__ dinv,
                                                       float* __restrict__ y, int N) {
    int t = blockIdx.x * 256 + threadIdx.x;              // one float4 per thread
    int total = N * (DIM / 4);
    if (t < total) {
        int row = t >> 5;                                 // DIM/4 = 32 float4 per row
        float di = dinv[row];
        float4 v = ((const float4*)x)[t];
        v.x *= di; v.y *= di; v.z *= di; v.w *= di;
        ((float4*)y)[t] = v;
    }
}

// ---------------- aggregation (pre-scaled): out[d] = dinv[d]*(y[d] + sum_e y[src]) ----------------
__global__ __launch_bounds__(256) void agg_kernel(const float* __restrict__ y,
                                                  const int* __restrict__ csr_src,
                                                  const int* __restrict__ offsets,
                                                  const float* __restrict__ dinv,
                                                  float* __restrict__ out, int N) {
    int lane = threadIdx.x & 63;
    int wid  = __builtin_amdgcn_readfirstlane((int)(threadIdx.x >> 6));
    int node = blockIdx.x * 4 + wid;
    if (node >= N) return;
    int beg = offsets[node];
    int end = offsets[node + 1];
    float di = dinv[node];
    float2 acc = ((const float2*)(y + (size_t)node * DIM))[lane];  // self term
    int j = beg;
    for (; j + 4 <= end; j += 4) {
        int s0 = csr_src[j + 0], s1 = csr_src[j + 1];
        int s2 = csr_src[j + 2], s3 = csr_src[j + 3];
        float2 v0 = ((const float2*)(y + (size_t)s0 * DIM))[lane];
        float2 v1 = ((const float2*)(y + (size_t)s1 * DIM))[lane];
        float2 v2 = ((const float2*)(y + (size_t)s2 * DIM))[lane];
        float2 v3 = ((const float2*)(y + (size_t)s3 * DIM))[lane];
        acc.x += v0.x; acc.y += v0.y;
        acc.x += v1.x; acc.y += v1.y;
        acc.x += v2.x; acc.y += v2.y;
        acc.x += v3.x; acc.y += v3.y;
    }
    for (; j < end; ++j) {
        int s = csr_src[j];
        float2 v = ((const float2*)(y + (size_t)s * DIM))[lane];
        acc.x += v.x; acc.y += v.y;
    }
    acc.x *= di; acc.y *= di;
    ((float2*)(out + (size_t)node * DIM))[lane] = acc;
}

// ---------------- aggregation fallback (no y buffer): fused dinv ----------------
__global__ __launch_bounds__(256) void agg_fused_kernel(const float* __restrict__ x,
                                                        const int* __restrict__ csr_src,
                                                        const int* __restrict__ offsets,
                                                        const float* __restrict__ dinv,
                                                        float* __restrict__ out, int N) {
    int lane = threadIdx.x & 63;
    int wid  = __builtin_amdgcn_readfirstlane((int)(threadIdx.x >> 6));
    int node = blockIdx.x * 4 + wid;
    if (node >= N) return;
    int beg = offsets[node];
    int end = offsets[node + 1];
    float di = dinv[node];
    float2 acc = ((const float2*)(x + (size_t)node * DIM))[lane];
    acc.x *= di; acc.y *= di;
    int j = beg;
    for (; j + 4 <= end; j += 4) {
        int s0 = csr_src[j + 0], s1 = csr_src[j + 1];
        int s2 = csr_src[j + 2], s3 = csr_src[j + 3];
        float w0 = dinv[s0], w1 = dinv[s1], w2 = dinv[s2], w3 = dinv[s3];
        float2 v0 = ((const float2*)(x + (size_t)s0 * DIM))[lane];
        float2 v1 = ((const float2*)(x + (size_t)s1 * DIM))[lane];
        float2 v2 = ((const float2*)(x + (size_t)s2 * DIM))[lane];
        float2 v3 = ((const float2*)(x + (size_t)s3 * DIM))[lane];
        acc.x += w0 * v0.x; acc.y += w0 * v0.y;
        acc.x += w1 * v1.x; acc.y += w1 * v1.y;
        acc.x += w2 * v2.x; acc.y += w2 * v2.y;
        acc.x += w3 * v3.x; acc.y += w3 * v3.y;
    }
    for (; j < end; ++j) {
        int s = csr_src[j];
        float w = dinv[s];
        float2 v = ((const float2*)(x + (size_t)s * DIM))[lane];
        acc.x += w * v.x; acc.y += w * v.y;
    }
    acc.x *= di; acc.y *= di;
    ((float2*)(out + (size_t)node * DIM))[lane] = acc;
}

// ---------------- in-place GEMM + bias + PReLU: io = prelu(io @ W + b) ----------------
__global__ __launch_bounds__(256) void gemm_kernel(float* __restrict__ io,
                                                   const float* __restrict__ W,
                                                   const float* __restrict__ b,
                                                   const float* __restrict__ alpha, int N) {
    int lane = threadIdx.x & 63;
    int wid  = __builtin_amdgcn_readfirstlane((int)(threadIdx.x >> 6));
    int rowbase = (blockIdx.x * 4 + wid) * 8;
    const int c0 = lane, c1 = lane + 64;
    float acc0[8], acc1[8];
    #pragma unroll
    for (int r = 0; r < 8; ++r) { acc0[r] = 0.f; acc1[r] = 0.f; }
    for (int k = 0; k < DIM; k += 4) {
        float w00 = W[(k + 0) * DIM + c0], w01 = W[(k + 1) * DIM + c0];
        float w02 = W[(k + 2) * DIM + c0], w03 = W[(k + 3) * DIM + c0];
        float w10 = W[(k + 0) * DIM + c1], w11 = W[(k + 1) * DIM + c1];
        float w12 = W[(k + 2) * DIM + c1], w13 = W[(k + 3) * DIM + c1];
        #pragma unroll
        for (int r = 0; r < 8; ++r) {
            int row = rowbase + r;
            row = row < N ? row : N - 1;
            float4 rv = ((const float4*)(io + (size_t)row * DIM))[k >> 2];
            acc0[r] += rv.x * w00 + rv.y * w01 + rv.z * w02 + rv.w * w03;
            acc1[r] += rv.x * w10 + rv.y * w11 + rv.z * w12 + rv.w * w13;
        }
    }
    float bb0 = b[c0], bb1 = b[c1], a0 = alpha[c0], a1 = alpha[c1];
    #pragma unroll
    for (int r = 0; r < 8; ++r) {
        int row = rowbase + r;
        if (row < N) {
            float v0 = acc0[r] + bb0; v0 = v0 > 0.f ? v0 : a0 * v0;
            float v1 = acc1[r] + bb1; v1 = v1 > 0.f ? v1 : a1 * v1;
            io[(size_t)row * DIM + c0] = v0;
            io[(size_t)row * DIM + c1] = v1;
        }
    }
}

extern "C" void kernel_launch(void* const* d_in, const int* in_sizes, int n_in,
                              void* d_out, int out_size, void* d_ws, size_t ws_size,
                              hipStream_t stream) {
    const float* x     = (const float*)d_in[0];
    const int*   ei    = (const int*)d_in[1];
    const float* W     = (const float*)d_in[2];
    const float* b     = (const float*)d_in[3];
    const float* alpha = (const float*)d_in[4];
    float* out = (float*)d_out;

    int N = in_sizes[0] / DIM;
    int E = in_sizes[1] / 2;
    const int* src = ei;
    const int* dst = ei + E;
    int nsb = (N + SCAN_BLOCK - 1) / SCAN_BLOCK;   // scan blocks (<=128 for N<=131072)

    char* ws = (char*)d_ws;
    size_t off = 0;
    auto alloc = [&](size_t bytes) -> char* {
        char* p = ws + off;
        off += (bytes + 255) & ~(size_t)255;
        return p;
    };
    int*   counts  = (int*)alloc((size_t)N * 4);
    int*   offsets = (int*)alloc((size_t)(N + 1) * 4);
    int*   cursor  = (int*)alloc((size_t)N * 4);
    float* dinv    = (float*)alloc((size_t)N * 4);
    int*   bsum    = (int*)alloc((size_t)nsb * 4);
    int*   boff    = (int*)alloc((size_t)nsb * 4);
    int*   csr_src = (int*)alloc((size_t)E * 4);
    size_t y_bytes = (size_t)N * DIM * 4;
    bool   have_y  = (off + y_bytes) <= ws_size;
    float* y       = have_y ? (float*)alloc(y_bytes) : nullptr;

    hipMemsetAsync(counts, 0, (size_t)N * 4, stream);
    hist_kernel<<<(E + 255) / 256, 256, 0, stream>>>(dst, counts, E);
    scan_reduce_kernel<<<nsb, SCAN_BLOCK, 0, stream>>>(counts, bsum, N);
    scan_bsums_kernel<<<1, 128, 0, stream>>>(bsum, boff, offsets, nsb, N);
    scan_apply_kernel<<<nsb, SCAN_BLOCK, 0, stream>>>(counts, boff, offsets, cursor, dinv, N);
    scatter_kernel<<<(E + 255) / 256, 256, 0, stream>>>(src, dst, cursor, csr_src, E);
    if (have_y) {
        prescale_kernel<<<(N * (DIM / 4) + 255) / 256, 256, 0, stream>>>(x, dinv, y, N);
        agg_kernel<<<(N + 3) / 4, 256, 0, stream>>>(y, csr_src, offsets, dinv, out, N);
    } else {
        agg_fused_kernel<<<(N + 3) / 4, 256, 0, stream>>>(x, csr_src, offsets, dinv, out, N);
    }
    gemm_kernel<<<(N + 31) / 32, 256, 0, stream>>>(out, W, b, alpha, N);
}